// Round 6
// baseline (5244.554 us; speedup 1.0000x reference)
//
#include <hip/hip_runtime.h>

// Neural SDE rollout, split-K across blocks. R5b: channel-spread exchange
// (resubmit of R5 -- previous bench died on container infra, not kernel).
// Unified model from R0-R4: per-step cost tracks cross-XCD coherence-point
// WORD TRANSACTIONS PER CHANNEL (~5cy each). Every prior variant kept each
// group's accumulator contiguous (4-32 KB) -> ~1-2 channels -> 8-16K
// serialized words/channel/step = the observed 17-33 us/step. R5 = R0's
// validated 2297us kernel with ONE change: accbuf (and counters) are
// interleaved element-major across groups (element e of group g at
// [e*NG+g], 256 B stride) so a group's 1024 words span 256 KB ~= all
// channels (~16 words/channel/step). Adds/loads/protocol byte-identical.

typedef _Float16 f16x8 __attribute__((ext_vector_type(8)));
typedef float    f32x4 __attribute__((ext_vector_type(4)));

#define MFMA(a,b,c) __builtin_amdgcn_mfma_f32_16x16x32_f16(a,b,c,0,0,0)

#define Bb 1024
#define Tt 128
#define NG 64          // groups
#define GB 8           // blocks per group (split-K over H=512 -> 64 cols each)
#define Rr 16          // rows per group (one MFMA M-tile)
#define NT 512         // threads per block (8 waves)

// packed fragment regions in d_ws (units: halves) -- identical pack to R0
#define W2SG_OFF 0
#define W2SG_HALVES (64*16*2*512)
#define W2MU_OFF (W2SG_OFF + W2SG_HALVES)
#define W2MU_HALVES (4*16*2*512)
#define W1MU_OFF (W2MU_OFF + W2MU_HALVES)
#define W1_HALVES (32*3*2*512)
#define W1SG_OFF (W1MU_OFF + W1_HALVES)
#define WS_HALVES (W1SG_OFF + W1_HALVES)
#define ACC_BYTES_OFF ((size_t)WS_HALVES * 2)
#define ACC_FLOATS (3 * NG * 1024)        // 3 slots x 64 groups x 16x64
#define CNT_BYTES_OFF (ACC_BYTES_OFF + (size_t)ACC_FLOATS * 4)
#define CNT_STRIDE 64                     // pad counters to 256 B (channel-spread)

// channel-spread accumulator addressing: element e of group g, slot s
#define ACC_IDX(s, g, e) (((size_t)(s)*1024 + (e))*NG + (g))

__global__ __launch_bounds__(256) void pack_weights(
    const float* __restrict__ W1_mu, const float* __restrict__ W2_mu,
    const float* __restrict__ W1_sg, const float* __restrict__ W2_sg,
    _Float16* __restrict__ wsh)
{
    int gid = blockIdx.x * 256 + threadIdx.x;
    if (gid >= 81920) return;
    const float* src; int ncols, kvalid; size_t dst;
    int id, tile, ks, lane;
    if (gid < 65536) {                 // W2_sg: 64 tiles x 16 ks x 64 lanes
        id = gid; tile = id >> 10; id &= 1023; ks = id >> 6; lane = id & 63;
        src = W2_sg; ncols = 1024; kvalid = 512;
        dst = W2SG_OFF + (size_t)((tile*16 + ks)*2) * 512 + lane*8;
    } else if (gid < 69632) {          // W2_mu: 4 x 16 x 64
        id = gid - 65536; tile = id >> 10; id &= 1023; ks = id >> 6; lane = id & 63;
        src = W2_mu; ncols = 64; kvalid = 512;
        dst = W2MU_OFF + (size_t)((tile*16 + ks)*2) * 512 + lane*8;
    } else if (gid < 75776) {          // W1_mu: 32 tiles x 3 ks x 64
        id = gid - 69632; tile = id / 192; id %= 192; ks = id >> 6; lane = id & 63;
        src = W1_mu; ncols = 512; kvalid = 80;
        dst = W1MU_OFF + (size_t)((tile*3 + ks)*2) * 512 + lane*8;
    } else {                           // W1_sg
        id = gid - 75776; tile = id / 192; id %= 192; ks = id >> 6; lane = id & 63;
        src = W1_sg; ncols = 512; kvalid = 80;
        dst = W1SG_OFF + (size_t)((tile*3 + ks)*2) * 512 + lane*8;
    }
    const int n  = tile*16 + (lane & 15);
    const int kb = ks*32 + ((lane >> 4) << 3);
    f16x8 hi8, lo8;
    #pragma unroll
    for (int jj = 0; jj < 8; ++jj) {
        int k = kb + jj;
        float wv = (k < kvalid) ? src[(size_t)k * ncols + n] : 0.f;
        _Float16 h = (_Float16)wv;
        hi8[jj] = h;
        lo8[jj] = (_Float16)(wv - (float)h);
    }
    *((f16x8*)(wsh + dst))       = hi8;
    *((f16x8*)(wsh + dst + 512)) = lo8;
}

__global__ __launch_bounds__(NT, 4) void nsde_spread(
    const float* __restrict__ y0, const float* __restrict__ controls,
    const float* __restrict__ noise,
    const float* __restrict__ b1_mu, const float* __restrict__ b2_mu,
    const float* __restrict__ b1_sg, const float* __restrict__ b2_sg,
    const _Float16* __restrict__ wf,
    float* __restrict__ accbuf, unsigned int* __restrict__ cnt,
    float* __restrict__ out)
{
    __shared__ _Float16 s_xhi[Rr][104], s_xlo[Rr][104];     // x, K=96 (+pad)
    __shared__ _Float16 s_hhi[2][Rr][72], s_hlo[2][Rr][72]; // h slices (64+pad)
    __shared__ float s_y[Rr*64];     // [r*64+n]
    __shared__ float s_dw[Rr][16];
    __shared__ float s_part[Rr*64];  // sg partial (dW-folded)
    __shared__ float s_pmu[Rr*64];   // mu partial (*dt)

    const int tid  = threadIdx.x;
    const int lane = tid & 63, w = tid >> 6;
    const int m15  = lane & 15, quad = lane >> 4;
    const int j    = blockIdx.x & 7;        // K-slice id
    const int g    = blockIdx.x >> 3;       // group
    const int r0   = g * Rr;

    // per-wave constants
    const int l  = w >> 2;                  // GEMM1 layer: 0=mu 1=sg
    const int ct = w & 3;                   // GEMM1 col-tile within slice
    const int tg = j*4 + ct;                // global W1 H-tile
    const _Float16* w1base = wf + (l ? W1SG_OFF : W1MU_OFF);
    const float bias1 = (l ? b1_sg : b1_mu)[j*64 + ct*16 + m15];
    float b2v[8];
    #pragma unroll
    for (int t = 0; t < 8; ++t)
        b2v[t] = (j == 0) ? b2_sg[(w + t*8)*16 + m15] : 0.f;
    const float b2m = (w < 4 && j == 0) ? b2_mu[w*16 + m15] * 0.01f : 0.f;

    // ---- init
    for (int e = tid; e < Rr*24; e += NT) {   // zero x K-pad cols 80..103
        int r = e / 24, c = 80 + e % 24;
        s_xhi[r][c] = (_Float16)0.f; s_xlo[r][c] = (_Float16)0.f;
    }
    if (tid < 256) {
        int e0 = tid*4, r = e0 >> 6, n = e0 & 63;
        float4 yv = *(const float4*)&y0[(size_t)(r0 + r)*64 + n];
        float vv[4] = {yv.x, yv.y, yv.z, yv.w};
        #pragma unroll
        for (int q = 0; q < 4; ++q) {
            s_y[e0+q] = vv[q];
            _Float16 h = (_Float16)vv[q];
            s_xhi[r][n+q] = h; s_xlo[r][n+q] = (_Float16)(vv[q] - (float)h);
        }
        if ((tid >> 5) == j)
            *(float4*)&out[(size_t)(r0 + r)*64 + n] = yv;
        int rr2 = tid >> 4, cc2 = tid & 15;
        float u = controls[cc2];
        _Float16 h = (_Float16)u;
        s_xhi[rr2][64+cc2] = h; s_xlo[rr2][64+cc2] = (_Float16)(u - (float)h);
        s_dw[rr2][cc2] = noise[(size_t)(r0 + rr2)*16 + cc2] * 0.1f;
    }
    __syncthreads();

    for (int k = 0; k < Tt-1; ++k) {
        // ======== GEMM1: one 16-col tile per wave, both layers in parallel
        {
            f32x4 a0 = {0,0,0,0}, a1 = {0,0,0,0}, a2 = {0,0,0,0};
            #pragma unroll
            for (int ks = 0; ks < 3; ++ks) {
                const _Float16* bp = w1base + (size_t)((tg*3 + ks)*2)*512 + lane*8;
                f16x8 bh = *(const f16x8*)bp;
                f16x8 bl = *(const f16x8*)(bp + 512);
                f16x8 ah = *(const f16x8*)&s_xhi[m15][ks*32 + quad*8];
                f16x8 al = *(const f16x8*)&s_xlo[m15][ks*32 + quad*8];
                a0 = MFMA(ah, bh, a0);
                a1 = MFMA(ah, bl, a1);
                a2 = MFMA(al, bh, a2);
            }
            f32x4 s = a0 + a1 + a2;
            #pragma unroll
            for (int rg = 0; rg < 4; ++rg) {
                int row = quad*4 + rg;
                float v = fmaxf(s[rg] + bias1, 0.f);
                _Float16 h = (_Float16)v;
                s_hhi[l][row][ct*16 + m15] = h;
                s_hlo[l][row][ct*16 + m15] = (_Float16)(v - (float)h);
            }
        }
        // prefetch next-step controls/noise into regs (hidden under GEMM2)
        float u_nx = 0.f, dw_nx = 0.f;
        const int r2 = tid >> 4, c2 = tid & 15;
        if (k < Tt-2 && tid < 256) {
            u_nx  = controls[(size_t)(k+1)*16 + c2];
            dw_nx = noise[((size_t)(k+1)*Bb + r0 + r2)*16 + c2] * 0.1f;
        }
        __syncthreads();

        // ======== GEMM2 over this block's K-slice (local k in [0,64))
        float dwv[4];
        #pragma unroll
        for (int rg = 0; rg < 4; ++rg)
            dwv[rg] = s_dw[quad*4 + rg][m15];

        // -- mu partial (waves 0..3 take n-tile w)
        if (w < 4) {
            f16x8 Mh0 = *(const f16x8*)&s_hhi[0][m15][quad*8];
            f16x8 Ml0 = *(const f16x8*)&s_hlo[0][m15][quad*8];
            f16x8 Mh1 = *(const f16x8*)&s_hhi[0][m15][32 + quad*8];
            f16x8 Ml1 = *(const f16x8*)&s_hlo[0][m15][32 + quad*8];
            const _Float16* bp = wf + W2MU_OFF + (size_t)((w*16 + 2*j)*2)*512 + lane*8;
            f16x8 bh0 = *(const f16x8*)(bp);
            f16x8 bl0 = *(const f16x8*)(bp + 512);
            f16x8 bh1 = *(const f16x8*)(bp + 1024);
            f16x8 bl1 = *(const f16x8*)(bp + 1536);
            f32x4 hh = {0,0,0,0}, hl = {0,0,0,0}, lh = {0,0,0,0};
            hh = MFMA(Mh0, bh0, hh); hl = MFMA(Mh0, bl0, hl); lh = MFMA(Ml0, bh0, lh);
            hh = MFMA(Mh1, bh1, hh); hl = MFMA(Mh1, bl1, hl); lh = MFMA(Ml1, bh1, lh);
            f32x4 s = hh + hl + lh;
            #pragma unroll
            for (int rg = 0; rg < 4; ++rg)
                s_pmu[(quad*4 + rg)*64 + w*16 + m15] = s[rg]*0.01f + b2m;
        }

        // -- sg partials: 8 n-tiles per wave
        f16x8 Ah0 = *(const f16x8*)&s_hhi[1][m15][quad*8];
        f16x8 Al0 = *(const f16x8*)&s_hlo[1][m15][quad*8];
        f16x8 Ah1 = *(const f16x8*)&s_hhi[1][m15][32 + quad*8];
        f16x8 Al1 = *(const f16x8*)&s_hlo[1][m15][32 + quad*8];
        #pragma unroll 2
        for (int t = 0; t < 8; ++t) {
            const int nt = w + t*8;
            const _Float16* bp = wf + W2SG_OFF + (size_t)((nt*16 + 2*j)*2)*512 + lane*8;
            f16x8 bh0 = *(const f16x8*)(bp);
            f16x8 bl0 = *(const f16x8*)(bp + 512);
            f16x8 bh1 = *(const f16x8*)(bp + 1024);
            f16x8 bl1 = *(const f16x8*)(bp + 1536);
            f32x4 hh = {0,0,0,0}, hl = {0,0,0,0}, lh = {0,0,0,0};
            hh = MFMA(Ah0, bh0, hh); hl = MFMA(Ah0, bl0, hl); lh = MFMA(Al0, bh0, lh);
            hh = MFMA(Ah1, bh1, hh); hl = MFMA(Ah1, bl1, hl); lh = MFMA(Al1, bh1, lh);
            f32x4 s = hh + hl + lh;
            #pragma unroll
            for (int rg = 0; rg < 4; ++rg) {
                float v = (s[rg] + b2v[t]) * dwv[rg];
                v += __shfl_xor(v, 1); v += __shfl_xor(v, 2);
                v += __shfl_xor(v, 4); v += __shfl_xor(v, 8);
                if (m15 == 0) s_part[(quad*4 + rg)*64 + nt] = v;
            }
        }
        __syncthreads();

        // ======== exchange: atomicAdd partials into slot k%3, CHANNEL-SPREAD
        const int slot = k % 3;
        const int e0 = tid*2;
        {
            float v0 = s_part[e0]   + s_pmu[e0];
            float v1 = s_part[e0+1] + s_pmu[e0+1];
            __hip_atomic_fetch_add(&accbuf[ACC_IDX(slot, g, e0)],   v0,
                                   __ATOMIC_RELAXED, __HIP_MEMORY_SCOPE_AGENT);
            __hip_atomic_fetch_add(&accbuf[ACC_IDX(slot, g, e0+1)], v1,
                                   __ATOMIC_RELAXED, __HIP_MEMORY_SCOPE_AGENT);
        }
        __syncthreads();   // drains vmcnt: all adds complete
        if (tid == 0) {
            __hip_atomic_fetch_add(&cnt[g*CNT_STRIDE], 1u, __ATOMIC_RELEASE,
                                   __HIP_MEMORY_SCOPE_AGENT);
            while (__hip_atomic_load(&cnt[g*CNT_STRIDE], __ATOMIC_RELAXED,
                                     __HIP_MEMORY_SCOPE_AGENT) < (unsigned)GB*(k+1))
                __builtin_amdgcn_s_sleep(2);
        }
        __syncthreads();

        // ======== read sum, y update, out write, next x/dW build
        {
            const int r = e0 >> 6, n = e0 & 63;
            float sum0 = __hip_atomic_load(&accbuf[ACC_IDX(slot, g, e0)],
                                           __ATOMIC_RELAXED, __HIP_MEMORY_SCOPE_AGENT);
            float sum1 = __hip_atomic_load(&accbuf[ACC_IDX(slot, g, e0+1)],
                                           __ATOMIC_RELAXED, __HIP_MEMORY_SCOPE_AGENT);
            float ya = s_y[e0]   + sum0;
            float yb = s_y[e0+1] + sum1;
            s_y[e0] = ya; s_y[e0+1] = yb;
            _Float16 ha = (_Float16)ya, hb = (_Float16)yb;
            s_xhi[r][n] = ha;   s_xlo[r][n]   = (_Float16)(ya - (float)ha);
            s_xhi[r][n+1] = hb; s_xlo[r][n+1] = (_Float16)(yb - (float)hb);
            if ((tid >> 6) == j) {   // wave j writes this block's 128-elem chunk
                float2 o = {ya, yb};
                *(float2*)&out[((size_t)(k+1)*Bb + r0 + r)*64 + n] = o;
                if (k >= 1) {        // zero slot (k-1)%3 (3-slot rotation safe)
                    const int zs = (k-1) % 3;
                    __hip_atomic_store(&accbuf[ACC_IDX(zs, g, e0)],   0.f,
                                       __ATOMIC_RELAXED, __HIP_MEMORY_SCOPE_AGENT);
                    __hip_atomic_store(&accbuf[ACC_IDX(zs, g, e0+1)], 0.f,
                                       __ATOMIC_RELAXED, __HIP_MEMORY_SCOPE_AGENT);
                }
            }
        }
        if (k < Tt-2 && tid < 256) {
            _Float16 h = (_Float16)u_nx;
            s_xhi[r2][64+c2] = h; s_xlo[r2][64+c2] = (_Float16)(u_nx - (float)h);
            s_dw[r2][c2] = dw_nx;
        }
        __syncthreads();
    }
}

extern "C" void kernel_launch(void* const* d_in, const int* in_sizes, int n_in,
                              void* d_out, int out_size, void* d_ws, size_t ws_size,
                              hipStream_t stream) {
    const float* y0       = (const float*)d_in[0];
    const float* controls = (const float*)d_in[1];
    const float* noise    = (const float*)d_in[2];
    const float* W1_mu    = (const float*)d_in[3];
    const float* b1_mu    = (const float*)d_in[4];
    const float* W2_mu    = (const float*)d_in[5];
    const float* b2_mu    = (const float*)d_in[6];
    const float* W1_sg    = (const float*)d_in[7];
    const float* b1_sg    = (const float*)d_in[8];
    const float* W2_sg    = (const float*)d_in[9];
    const float* b2_sg    = (const float*)d_in[10];
    float* out = (float*)d_out;
    _Float16* wsh = (_Float16*)d_ws;
    float* accbuf = (float*)((char*)d_ws + ACC_BYTES_OFF);
    unsigned int* cnt = (unsigned int*)((char*)d_ws + CNT_BYTES_OFF);

    // zero accumulator slots + padded counters (ws is poisoned 0xAA each call)
    hipMemsetAsync((char*)d_ws + ACC_BYTES_OFF, 0,
                   (size_t)ACC_FLOATS*4 + (size_t)NG*CNT_STRIDE*4, stream);
    pack_weights<<<320, 256, 0, stream>>>(W1_mu, W2_mu, W1_sg, W2_sg, wsh);
    nsde_spread<<<NG*GB, NT, 0, stream>>>(y0, controls, noise,
                                          b1_mu, b2_mu, b1_sg, b2_sg,
                                          (const _Float16*)wsh,
                                          accbuf, cnt, out);
}

// Round 7
// 4057.171 us; speedup vs baseline: 1.2927x; 1.2927x over previous
//
#include <hip/hip_runtime.h>

// Neural SDE rollout, split-K across blocks. R6: GB=4, fewer exchange lines.
// Surviving empirical law after R0-R5: per-step cost scales linearly with
// LINE-granular RMW transactions per group region (R0: 512 -> 18.1us/step;
// R4: 1024 -> 33.6; R5b word-spread: 6x traffic, 2.3x time). Lever: reduce
// writers per group. R6 = NG=128 groups x Rr=8 rows, GB=4 blocks/group
// (128-col H-slices) -> 512 blocks x 512 thr, 2 blocks/CU preserved
// (the proven-necessary co-residency). Per-group exchange: 32 lines x 4
// writers = 128 line-RMWs/step (4x fewer than R0). M-tile rows 8..15 are
// zero-padded garbage, masked from exchange (dW=0 rows + row<8 guards).
// Exchange protocol (3-slot atomicAdd rotation + release counter) verbatim R0.

typedef _Float16 f16x8 __attribute__((ext_vector_type(8)));
typedef float    f32x4 __attribute__((ext_vector_type(4)));

#define MFMA(a,b,c) __builtin_amdgcn_mfma_f32_16x16x32_f16(a,b,c,0,0,0)

#define Bb 1024
#define Tt 128
#define NG 128         // groups
#define GB 4           // blocks per group (split-K over H=512 -> 128 cols each)
#define Rr 8           // rows per group (half an MFMA M-tile; rows 8..15 padded)
#define NT 512         // threads per block (8 waves)

// packed fragment regions in d_ws (units: halves) -- identical pack to R0
#define W2SG_OFF 0
#define W2SG_HALVES (64*16*2*512)
#define W2MU_OFF (W2SG_OFF + W2SG_HALVES)
#define W2MU_HALVES (4*16*2*512)
#define W1MU_OFF (W2MU_OFF + W2MU_HALVES)
#define W1_HALVES (32*3*2*512)
#define W1SG_OFF (W1MU_OFF + W1_HALVES)
#define WS_HALVES (W1SG_OFF + W1_HALVES)
#define ACC_BYTES_OFF ((size_t)WS_HALVES * 2)
#define ACC_FLOATS (3 * NG * (Rr*64))     // 3 slots x 128 groups x 8x64
#define CNT_BYTES_OFF (ACC_BYTES_OFF + (size_t)ACC_FLOATS * 4)
#define CNT_STRIDE 16                     // pad counters to 64 B

__global__ __launch_bounds__(256) void pack_weights(
    const float* __restrict__ W1_mu, const float* __restrict__ W2_mu,
    const float* __restrict__ W1_sg, const float* __restrict__ W2_sg,
    _Float16* __restrict__ wsh)
{
    int gid = blockIdx.x * 256 + threadIdx.x;
    if (gid >= 81920) return;
    const float* src; int ncols, kvalid; size_t dst;
    int id, tile, ks, lane;
    if (gid < 65536) {                 // W2_sg: 64 tiles x 16 ks x 64 lanes
        id = gid; tile = id >> 10; id &= 1023; ks = id >> 6; lane = id & 63;
        src = W2_sg; ncols = 1024; kvalid = 512;
        dst = W2SG_OFF + (size_t)((tile*16 + ks)*2) * 512 + lane*8;
    } else if (gid < 69632) {          // W2_mu: 4 x 16 x 64
        id = gid - 65536; tile = id >> 10; id &= 1023; ks = id >> 6; lane = id & 63;
        src = W2_mu; ncols = 64; kvalid = 512;
        dst = W2MU_OFF + (size_t)((tile*16 + ks)*2) * 512 + lane*8;
    } else if (gid < 75776) {          // W1_mu: 32 tiles x 3 ks x 64
        id = gid - 69632; tile = id / 192; id %= 192; ks = id >> 6; lane = id & 63;
        src = W1_mu; ncols = 512; kvalid = 80;
        dst = W1MU_OFF + (size_t)((tile*3 + ks)*2) * 512 + lane*8;
    } else {                           // W1_sg
        id = gid - 75776; tile = id / 192; id %= 192; ks = id >> 6; lane = id & 63;
        src = W1_sg; ncols = 512; kvalid = 80;
        dst = W1SG_OFF + (size_t)((tile*3 + ks)*2) * 512 + lane*8;
    }
    const int n  = tile*16 + (lane & 15);
    const int kb = ks*32 + ((lane >> 4) << 3);
    f16x8 hi8, lo8;
    #pragma unroll
    for (int jj = 0; jj < 8; ++jj) {
        int k = kb + jj;
        float wv = (k < kvalid) ? src[(size_t)k * ncols + n] : 0.f;
        _Float16 h = (_Float16)wv;
        hi8[jj] = h;
        lo8[jj] = (_Float16)(wv - (float)h);
    }
    *((f16x8*)(wsh + dst))       = hi8;
    *((f16x8*)(wsh + dst + 512)) = lo8;
}

__global__ __launch_bounds__(NT, 4) void nsde_gb4(
    const float* __restrict__ y0, const float* __restrict__ controls,
    const float* __restrict__ noise,
    const float* __restrict__ b1_mu, const float* __restrict__ b2_mu,
    const float* __restrict__ b1_sg, const float* __restrict__ b2_sg,
    const _Float16* __restrict__ wf,
    float* __restrict__ accbuf, unsigned int* __restrict__ cnt,
    float* __restrict__ out)
{
    __shared__ _Float16 s_xhi[16][104], s_xlo[16][104];     // x, K=96 (+pad); rows 8..15 zero
    __shared__ _Float16 s_hhi[2][16][136], s_hlo[2][16][136]; // h slices (128+pad)
    __shared__ float s_y[Rr*64];     // [r*64+n], 512
    __shared__ float s_dw[16][16];   // rows 8..15 zero
    __shared__ float s_part[Rr*64];  // sg partial (dW-folded), valid rows only
    __shared__ float s_pmu[Rr*64];   // mu partial (*dt)

    const int tid  = threadIdx.x;
    const int lane = tid & 63, w = tid >> 6;
    const int m15  = lane & 15, quad = lane >> 4;
    const int j    = blockIdx.x & 3;        // K-slice id (128 cols)
    const int g    = blockIdx.x >> 2;       // group
    const int r0   = g * Rr;

    // per-wave GEMM1 constants: layer l, two col-tiles ctb and ctb+4
    const int l   = w >> 2;                 // 0=mu 1=sg
    const int ctb = w & 3;
    const _Float16* w1base = wf + (l ? W1SG_OFF : W1MU_OFF);
    float bias1[2];
    bias1[0] = (l ? b1_sg : b1_mu)[j*128 + ctb*16 + m15];
    bias1[1] = (l ? b1_sg : b1_mu)[j*128 + (ctb+4)*16 + m15];
    float b2v[8];
    #pragma unroll
    for (int t = 0; t < 8; ++t)
        b2v[t] = (j == 0) ? b2_sg[(w + t*8)*16 + m15] : 0.f;
    const float b2m = (w < 4 && j == 0) ? b2_mu[w*16 + m15] * 0.01f : 0.f;

    // ---- init: zero ALL x (rows 8..15 + pad cols stay zero forever) and dW
    for (int e = tid; e < 16*104; e += NT) {
        int r = e / 104, c = e % 104;
        s_xhi[r][c] = (_Float16)0.f; s_xlo[r][c] = (_Float16)0.f;
    }
    if (tid < 256) s_dw[tid >> 4][tid & 15] = 0.f;
    __syncthreads();
    if (tid < 128) {
        // y fill: 512 floats, float4 per thread
        int e0 = tid*4, r = e0 >> 6, n = e0 & 63;
        float4 yv = *(const float4*)&y0[(size_t)(r0 + r)*64 + n];
        float vv[4] = {yv.x, yv.y, yv.z, yv.w};
        #pragma unroll
        for (int q = 0; q < 4; ++q) {
            s_y[e0+q] = vv[q];
            _Float16 h = (_Float16)vv[q];
            s_xhi[r][n+q] = h; s_xlo[r][n+q] = (_Float16)(vv[q] - (float)h);
        }
        if ((tid >> 5) == j)                 // block j writes its 1/4 chunk
            *(float4*)&out[(size_t)(r0 + r)*64 + n] = yv;
        // u + dW fill (rows 0..7)
        int r2 = tid >> 4, c2 = tid & 15;
        float u = controls[c2];
        _Float16 h = (_Float16)u;
        s_xhi[r2][64+c2] = h; s_xlo[r2][64+c2] = (_Float16)(u - (float)h);
        s_dw[r2][c2] = noise[(size_t)(r0 + r2)*16 + c2] * 0.1f;
    }
    __syncthreads();

    for (int k = 0; k < Tt-1; ++k) {
        // ======== GEMM1: two 16-col tiles per wave, both layers across waves
        #pragma unroll
        for (int tt = 0; tt < 2; ++tt) {
            const int ct = ctb + tt*4;
            const int tg = j*8 + ct;
            f32x4 a0 = {0,0,0,0}, a1 = {0,0,0,0}, a2 = {0,0,0,0};
            #pragma unroll
            for (int ks = 0; ks < 3; ++ks) {
                const _Float16* bp = w1base + (size_t)((tg*3 + ks)*2)*512 + lane*8;
                f16x8 bh = *(const f16x8*)bp;
                f16x8 bl = *(const f16x8*)(bp + 512);
                f16x8 ah = *(const f16x8*)&s_xhi[m15][ks*32 + quad*8];
                f16x8 al = *(const f16x8*)&s_xlo[m15][ks*32 + quad*8];
                a0 = MFMA(ah, bh, a0);
                a1 = MFMA(ah, bl, a1);
                a2 = MFMA(al, bh, a2);
            }
            f32x4 s = a0 + a1 + a2;
            #pragma unroll
            for (int rg = 0; rg < 4; ++rg) {
                int row = quad*4 + rg;
                float v = fmaxf(s[rg] + bias1[tt], 0.f);
                _Float16 h = (_Float16)v;
                s_hhi[l][row][ct*16 + m15] = h;
                s_hlo[l][row][ct*16 + m15] = (_Float16)(v - (float)h);
            }
        }
        // prefetch next-step controls/noise into regs (hidden under GEMM2)
        float u_nx = 0.f, dw_nx = 0.f;
        const int r2 = tid >> 4, c2 = tid & 15;
        if (k < Tt-2 && tid < 128) {
            u_nx  = controls[(size_t)(k+1)*16 + c2];
            dw_nx = noise[((size_t)(k+1)*Bb + r0 + r2)*16 + c2] * 0.1f;
        }
        __syncthreads();

        // ======== GEMM2 over this block's K-slice (local k in [0,128))
        float dwv[4];
        #pragma unroll
        for (int rg = 0; rg < 4; ++rg)
            dwv[rg] = s_dw[quad*4 + rg][m15];   // rows 8..15 read zeros

        // -- mu partial (waves 0..3 take n-tile w)
        if (w < 4) {
            f32x4 hh = {0,0,0,0}, hl = {0,0,0,0}, lh = {0,0,0,0};
            #pragma unroll
            for (int kk = 0; kk < 4; ++kk) {
                f16x8 Mh = *(const f16x8*)&s_hhi[0][m15][kk*32 + quad*8];
                f16x8 Ml = *(const f16x8*)&s_hlo[0][m15][kk*32 + quad*8];
                const _Float16* bp = wf + W2MU_OFF
                    + (size_t)((w*16 + (4*j + kk))*2)*512 + lane*8;
                f16x8 bh = *(const f16x8*)(bp);
                f16x8 bl = *(const f16x8*)(bp + 512);
                hh = MFMA(Mh, bh, hh); hl = MFMA(Mh, bl, hl); lh = MFMA(Ml, bh, lh);
            }
            f32x4 s = hh + hl + lh;
            #pragma unroll
            for (int rg = 0; rg < 4; ++rg) {
                int row = quad*4 + rg;
                if (row < 8)
                    s_pmu[row*64 + w*16 + m15] = s[rg]*0.01f + b2m;
            }
        }

        // -- sg partials: 8 n-tiles per wave, K=128 slice (4 fragments hoisted)
        f16x8 Ah[4], Al[4];
        #pragma unroll
        for (int kk = 0; kk < 4; ++kk) {
            Ah[kk] = *(const f16x8*)&s_hhi[1][m15][kk*32 + quad*8];
            Al[kk] = *(const f16x8*)&s_hlo[1][m15][kk*32 + quad*8];
        }
        #pragma unroll 2
        for (int t = 0; t < 8; ++t) {
            const int nt = w + t*8;
            f32x4 hh = {0,0,0,0}, hl = {0,0,0,0}, lh = {0,0,0,0};
            #pragma unroll
            for (int kk = 0; kk < 4; ++kk) {
                const _Float16* bp = wf + W2SG_OFF
                    + (size_t)((nt*16 + (4*j + kk))*2)*512 + lane*8;
                f16x8 bh = *(const f16x8*)(bp);
                f16x8 bl = *(const f16x8*)(bp + 512);
                hh = MFMA(Ah[kk], bh, hh); hl = MFMA(Ah[kk], bl, hl);
                lh = MFMA(Al[kk], bh, lh);
            }
            f32x4 s = hh + hl + lh;
            #pragma unroll
            for (int rg = 0; rg < 4; ++rg) {
                float v = (s[rg] + b2v[t]) * dwv[rg];
                v += __shfl_xor(v, 1); v += __shfl_xor(v, 2);
                v += __shfl_xor(v, 4); v += __shfl_xor(v, 8);
                int row = quad*4 + rg;
                if (m15 == 0 && row < 8) s_part[row*64 + nt] = v;
            }
        }
        __syncthreads();

        // ======== exchange: atomicAdd partials into slot k%3 (validated R0)
        const int slot = k % 3;
        float* ab = accbuf + ((size_t)slot*NG + g)*(Rr*64);
        {
            float v = s_part[tid] + s_pmu[tid];   // tid in [0,512)
            __hip_atomic_fetch_add(&ab[tid], v, __ATOMIC_RELAXED,
                                   __HIP_MEMORY_SCOPE_AGENT);
        }
        __syncthreads();   // drains vmcnt: all adds complete
        if (tid == 0) {
            __hip_atomic_fetch_add(&cnt[g*CNT_STRIDE], 1u, __ATOMIC_RELEASE,
                                   __HIP_MEMORY_SCOPE_AGENT);
            while (__hip_atomic_load(&cnt[g*CNT_STRIDE], __ATOMIC_RELAXED,
                                     __HIP_MEMORY_SCOPE_AGENT) < (unsigned)GB*(k+1))
                __builtin_amdgcn_s_sleep(2);
        }
        __syncthreads();

        // ======== read sum, y update, out write, next x/dW build
        {
            const int r = tid >> 6, n = tid & 63;
            float sum = __hip_atomic_load(&ab[tid], __ATOMIC_RELAXED,
                                          __HIP_MEMORY_SCOPE_AGENT);
            float yn = s_y[tid] + sum;
            s_y[tid] = yn;
            _Float16 h = (_Float16)yn;
            s_xhi[r][n] = h;
            s_xlo[r][n] = (_Float16)(yn - (float)h);
            if ((tid >> 7) == j) {   // block j writes its 128-elem chunk
                out[((size_t)(k+1)*Bb + r0 + r)*64 + n] = yn;
                if (k >= 1) {        // zero slot (k-1)%3 (3-slot rotation safe)
                    float* zb = accbuf + ((size_t)((k-1)%3)*NG + g)*(Rr*64);
                    __hip_atomic_store(&zb[tid], 0.f, __ATOMIC_RELAXED,
                                       __HIP_MEMORY_SCOPE_AGENT);
                }
            }
        }
        if (k < Tt-2 && tid < 128) {
            _Float16 h = (_Float16)u_nx;
            s_xhi[r2][64+c2] = h; s_xlo[r2][64+c2] = (_Float16)(u_nx - (float)h);
            s_dw[r2][c2] = dw_nx;
        }
        __syncthreads();
    }
}

extern "C" void kernel_launch(void* const* d_in, const int* in_sizes, int n_in,
                              void* d_out, int out_size, void* d_ws, size_t ws_size,
                              hipStream_t stream) {
    const float* y0       = (const float*)d_in[0];
    const float* controls = (const float*)d_in[1];
    const float* noise    = (const float*)d_in[2];
    const float* W1_mu    = (const float*)d_in[3];
    const float* b1_mu    = (const float*)d_in[4];
    const float* W2_mu    = (const float*)d_in[5];
    const float* b2_mu    = (const float*)d_in[6];
    const float* W1_sg    = (const float*)d_in[7];
    const float* b1_sg    = (const float*)d_in[8];
    const float* W2_sg    = (const float*)d_in[9];
    const float* b2_sg    = (const float*)d_in[10];
    float* out = (float*)d_out;
    _Float16* wsh = (_Float16*)d_ws;
    float* accbuf = (float*)((char*)d_ws + ACC_BYTES_OFF);
    unsigned int* cnt = (unsigned int*)((char*)d_ws + CNT_BYTES_OFF);

    // zero accumulator slots + padded counters (ws is poisoned 0xAA each call)
    hipMemsetAsync((char*)d_ws + ACC_BYTES_OFF, 0,
                   (size_t)ACC_FLOATS*4 + (size_t)NG*CNT_STRIDE*4, stream);
    pack_weights<<<320, 256, 0, stream>>>(W1_mu, W2_mu, W1_sg, W2_sg, wsh);
    nsde_gb4<<<NG*GB, NT, 0, stream>>>(y0, controls, noise,
                                       b1_mu, b2_mu, b1_sg, b2_sg,
                                       (const _Float16*)wsh,
                                       accbuf, cnt, out);
}

// Round 8
// 2535.070 us; speedup vs baseline: 2.0688x; 1.6004x over previous
//
#include <hip/hip_runtime.h>

// Neural SDE rollout, split-K across blocks. R7: consolidation on the R0
// structure (the only one that works: NG=64 x GB=8 x 16 rows, 512 blocks,
// 2 blocks/CU from independent sync domains, coalesced 3-slot atomicAdd
// exchange + release counter). Seven structural probes all regressed;
// this round banks measured micro-costs instead:
//  1) LDS repad: s_x stride 104->106 halves (53 words, gcd(21,32)=1),
//     s_h 72->74 (37 words) -> bank-conflict-free row maps
//     (SQ_LDS_BANK_CONFLICT was 6.45e7 ~= 4.5% of runtime).
//  2) Spin-window precompute: GEMM1's ks=2 slice depends only on u_{k+1}
//     (known pre-exchange). u/dW LDS write moved before the drain barrier;
//     the 3 ks=2 MFMAs execute while tid0 spins. Release-inc issued FIRST.
//  3) Old-slot zeroing moved to wave (j+4)&7, parallel with wave j's
//     out-write (still block-bijective over the group).

typedef _Float16 f16x8 __attribute__((ext_vector_type(8)));
typedef float    f32x4 __attribute__((ext_vector_type(4)));

#define MFMA(a,b,c) __builtin_amdgcn_mfma_f32_16x16x32_f16(a,b,c,0,0,0)

#define Bb 1024
#define Tt 128
#define NG 64          // groups
#define GB 8           // blocks per group (split-K over H=512 -> 64 cols each)
#define Rr 16          // rows per group (one MFMA M-tile)
#define NT 512         // threads per block (8 waves)
#define XP 106         // s_x row stride in halves (53 words, odd -> gcd(.,32)=1)
#define HP 74          // s_h row stride in halves (37 words, odd)

// packed fragment regions in d_ws (units: halves) -- identical pack to R0
#define W2SG_OFF 0
#define W2SG_HALVES (64*16*2*512)
#define W2MU_OFF (W2SG_OFF + W2SG_HALVES)
#define W2MU_HALVES (4*16*2*512)
#define W1MU_OFF (W2MU_OFF + W2MU_HALVES)
#define W1_HALVES (32*3*2*512)
#define W1SG_OFF (W1MU_OFF + W1_HALVES)
#define WS_HALVES (W1SG_OFF + W1_HALVES)
#define ACC_BYTES_OFF ((size_t)WS_HALVES * 2)
#define ACC_FLOATS (3 * NG * 1024)        // 3 slots x 64 groups x 16x64
#define CNT_BYTES_OFF (ACC_BYTES_OFF + (size_t)ACC_FLOATS * 4)
#define CNT_STRIDE 16                     // pad counters to 64 B

__global__ __launch_bounds__(256) void pack_weights(
    const float* __restrict__ W1_mu, const float* __restrict__ W2_mu,
    const float* __restrict__ W1_sg, const float* __restrict__ W2_sg,
    _Float16* __restrict__ wsh)
{
    int gid = blockIdx.x * 256 + threadIdx.x;
    if (gid >= 81920) return;
    const float* src; int ncols, kvalid; size_t dst;
    int id, tile, ks, lane;
    if (gid < 65536) {                 // W2_sg: 64 tiles x 16 ks x 64 lanes
        id = gid; tile = id >> 10; id &= 1023; ks = id >> 6; lane = id & 63;
        src = W2_sg; ncols = 1024; kvalid = 512;
        dst = W2SG_OFF + (size_t)((tile*16 + ks)*2) * 512 + lane*8;
    } else if (gid < 69632) {          // W2_mu: 4 x 16 x 64
        id = gid - 65536; tile = id >> 10; id &= 1023; ks = id >> 6; lane = id & 63;
        src = W2_mu; ncols = 64; kvalid = 512;
        dst = W2MU_OFF + (size_t)((tile*16 + ks)*2) * 512 + lane*8;
    } else if (gid < 75776) {          // W1_mu: 32 tiles x 3 ks x 64
        id = gid - 69632; tile = id / 192; id %= 192; ks = id >> 6; lane = id & 63;
        src = W1_mu; ncols = 512; kvalid = 80;
        dst = W1MU_OFF + (size_t)((tile*3 + ks)*2) * 512 + lane*8;
    } else {                           // W1_sg
        id = gid - 75776; tile = id / 192; id %= 192; ks = id >> 6; lane = id & 63;
        src = W1_sg; ncols = 512; kvalid = 80;
        dst = W1SG_OFF + (size_t)((tile*3 + ks)*2) * 512 + lane*8;
    }
    const int n  = tile*16 + (lane & 15);
    const int kb = ks*32 + ((lane >> 4) << 3);
    f16x8 hi8, lo8;
    #pragma unroll
    for (int jj = 0; jj < 8; ++jj) {
        int k = kb + jj;
        float wv = (k < kvalid) ? src[(size_t)k * ncols + n] : 0.f;
        _Float16 h = (_Float16)wv;
        hi8[jj] = h;
        lo8[jj] = (_Float16)(wv - (float)h);
    }
    *((f16x8*)(wsh + dst))       = hi8;
    *((f16x8*)(wsh + dst + 512)) = lo8;
}

__global__ __launch_bounds__(NT, 4) void nsde_r7(
    const float* __restrict__ y0, const float* __restrict__ controls,
    const float* __restrict__ noise,
    const float* __restrict__ b1_mu, const float* __restrict__ b2_mu,
    const float* __restrict__ b1_sg, const float* __restrict__ b2_sg,
    const _Float16* __restrict__ wf,
    float* __restrict__ accbuf, unsigned int* __restrict__ cnt,
    float* __restrict__ out)
{
    __shared__ _Float16 s_xhi[Rr][XP], s_xlo[Rr][XP];       // x, K=96 (+pad)
    __shared__ _Float16 s_hhi[2][Rr][HP], s_hlo[2][Rr][HP]; // h slices (64+pad)
    __shared__ float s_y[Rr*64];     // [r*64+n]
    __shared__ float s_dw[Rr][16];
    __shared__ float s_part[Rr*64];  // sg partial (dW-folded)
    __shared__ float s_pmu[Rr*64];   // mu partial (*dt)

    const int tid  = threadIdx.x;
    const int lane = tid & 63, w = tid >> 6;
    const int m15  = lane & 15, quad = lane >> 4;
    const int j    = blockIdx.x & 7;        // K-slice id
    const int g    = blockIdx.x >> 3;       // group
    const int r0   = g * Rr;

    // per-wave constants
    const int l  = w >> 2;                  // GEMM1 layer: 0=mu 1=sg
    const int ct = w & 3;                   // GEMM1 col-tile within slice
    const int tg = j*4 + ct;                // global W1 H-tile
    const _Float16* w1base = wf + (l ? W1SG_OFF : W1MU_OFF);
    const float bias1 = (l ? b1_sg : b1_mu)[j*64 + ct*16 + m15];
    float b2v[8];
    #pragma unroll
    for (int t = 0; t < 8; ++t)
        b2v[t] = (j == 0) ? b2_sg[(w + t*8)*16 + m15] : 0.f;
    const float b2m = (w < 4 && j == 0) ? b2_mu[w*16 + m15] * 0.01f : 0.f;

    // ---- init
    for (int e = tid; e < Rr*26; e += NT) {   // zero x K-pad cols 80..105
        int r = e / 26, c = 80 + e % 26;
        s_xhi[r][c] = (_Float16)0.f; s_xlo[r][c] = (_Float16)0.f;
    }
    if (tid < 256) {
        int e0 = tid*4, r = e0 >> 6, n = e0 & 63;
        float4 yv = *(const float4*)&y0[(size_t)(r0 + r)*64 + n];
        float vv[4] = {yv.x, yv.y, yv.z, yv.w};
        #pragma unroll
        for (int q = 0; q < 4; ++q) {
            s_y[e0+q] = vv[q];
            _Float16 h = (_Float16)vv[q];
            s_xhi[r][n+q] = h; s_xlo[r][n+q] = (_Float16)(vv[q] - (float)h);
        }
        if ((tid >> 5) == j)
            *(float4*)&out[(size_t)(r0 + r)*64 + n] = yv;
        int rr2 = tid >> 4, cc2 = tid & 15;
        float u = controls[cc2];
        _Float16 h = (_Float16)u;
        s_xhi[rr2][64+cc2] = h; s_xlo[rr2][64+cc2] = (_Float16)(u - (float)h);
        s_dw[rr2][cc2] = noise[(size_t)(r0 + rr2)*16 + cc2] * 0.1f;
    }
    __syncthreads();

    // ---- pre-loop: ks=2 (u-part) GEMM1 precompute for step 0
    f32x4 pre0 = {0,0,0,0}, pre1 = {0,0,0,0}, pre2 = {0,0,0,0};
    {
        const _Float16* bp = w1base + (size_t)((tg*3 + 2)*2)*512 + lane*8;
        f16x8 bh = *(const f16x8*)bp;
        f16x8 bl = *(const f16x8*)(bp + 512);
        f16x8 ah = *(const f16x8*)&s_xhi[m15][64 + quad*8];
        f16x8 al = *(const f16x8*)&s_xlo[m15][64 + quad*8];
        pre0 = MFMA(ah, bh, pre0);
        pre1 = MFMA(ah, bl, pre1);
        pre2 = MFMA(al, bh, pre2);
    }

    for (int k = 0; k < Tt-1; ++k) {
        // ======== GEMM1: ks 0,1 on top of precomputed ks=2 (u-part)
        {
            f32x4 a0 = pre0, a1 = pre1, a2 = pre2;
            #pragma unroll
            for (int ks = 0; ks < 2; ++ks) {
                const _Float16* bp = w1base + (size_t)((tg*3 + ks)*2)*512 + lane*8;
                f16x8 bh = *(const f16x8*)bp;
                f16x8 bl = *(const f16x8*)(bp + 512);
                f16x8 ah = *(const f16x8*)&s_xhi[m15][ks*32 + quad*8];
                f16x8 al = *(const f16x8*)&s_xlo[m15][ks*32 + quad*8];
                a0 = MFMA(ah, bh, a0);
                a1 = MFMA(ah, bl, a1);
                a2 = MFMA(al, bh, a2);
            }
            f32x4 s = a0 + a1 + a2;
            #pragma unroll
            for (int rg = 0; rg < 4; ++rg) {
                int row = quad*4 + rg;
                float v = fmaxf(s[rg] + bias1, 0.f);
                _Float16 h = (_Float16)v;
                s_hhi[l][row][ct*16 + m15] = h;
                s_hlo[l][row][ct*16 + m15] = (_Float16)(v - (float)h);
            }
        }
        // prefetch next-step controls/noise into regs (hidden under GEMM2)
        float u_nx = 0.f, dw_nx = 0.f;
        const int r2 = tid >> 4, c2 = tid & 15;
        if (k < Tt-2 && tid < 256) {
            u_nx  = controls[(size_t)(k+1)*16 + c2];
            dw_nx = noise[((size_t)(k+1)*Bb + r0 + r2)*16 + c2] * 0.1f;
        }
        __syncthreads();

        // ======== GEMM2 over this block's K-slice (local k in [0,64))
        float dwv[4];
        #pragma unroll
        for (int rg = 0; rg < 4; ++rg)
            dwv[rg] = s_dw[quad*4 + rg][m15];

        // -- mu partial (waves 0..3 take n-tile w)
        if (w < 4) {
            f16x8 Mh0 = *(const f16x8*)&s_hhi[0][m15][quad*8];
            f16x8 Ml0 = *(const f16x8*)&s_hlo[0][m15][quad*8];
            f16x8 Mh1 = *(const f16x8*)&s_hhi[0][m15][32 + quad*8];
            f16x8 Ml1 = *(const f16x8*)&s_hlo[0][m15][32 + quad*8];
            const _Float16* bp = wf + W2MU_OFF + (size_t)((w*16 + 2*j)*2)*512 + lane*8;
            f16x8 bh0 = *(const f16x8*)(bp);
            f16x8 bl0 = *(const f16x8*)(bp + 512);
            f16x8 bh1 = *(const f16x8*)(bp + 1024);
            f16x8 bl1 = *(const f16x8*)(bp + 1536);
            f32x4 hh = {0,0,0,0}, hl = {0,0,0,0}, lh = {0,0,0,0};
            hh = MFMA(Mh0, bh0, hh); hl = MFMA(Mh0, bl0, hl); lh = MFMA(Ml0, bh0, lh);
            hh = MFMA(Mh1, bh1, hh); hl = MFMA(Mh1, bl1, hl); lh = MFMA(Ml1, bh1, lh);
            f32x4 s = hh + hl + lh;
            #pragma unroll
            for (int rg = 0; rg < 4; ++rg)
                s_pmu[(quad*4 + rg)*64 + w*16 + m15] = s[rg]*0.01f + b2m;
        }

        // -- sg partials: 8 n-tiles per wave
        f16x8 Ah0 = *(const f16x8*)&s_hhi[1][m15][quad*8];
        f16x8 Al0 = *(const f16x8*)&s_hlo[1][m15][quad*8];
        f16x8 Ah1 = *(const f16x8*)&s_hhi[1][m15][32 + quad*8];
        f16x8 Al1 = *(const f16x8*)&s_hlo[1][m15][32 + quad*8];
        #pragma unroll 2
        for (int t = 0; t < 8; ++t) {
            const int nt = w + t*8;
            const _Float16* bp = wf + W2SG_OFF + (size_t)((nt*16 + 2*j)*2)*512 + lane*8;
            f16x8 bh0 = *(const f16x8*)(bp);
            f16x8 bl0 = *(const f16x8*)(bp + 512);
            f16x8 bh1 = *(const f16x8*)(bp + 1024);
            f16x8 bl1 = *(const f16x8*)(bp + 1536);
            f32x4 hh = {0,0,0,0}, hl = {0,0,0,0}, lh = {0,0,0,0};
            hh = MFMA(Ah0, bh0, hh); hl = MFMA(Ah0, bl0, hl); lh = MFMA(Al0, bh0, lh);
            hh = MFMA(Ah1, bh1, hh); hl = MFMA(Ah1, bl1, hl); lh = MFMA(Al1, bh1, lh);
            f32x4 s = hh + hl + lh;
            #pragma unroll
            for (int rg = 0; rg < 4; ++rg) {
                float v = (s[rg] + b2v[t]) * dwv[rg];
                v += __shfl_xor(v, 1); v += __shfl_xor(v, 2);
                v += __shfl_xor(v, 4); v += __shfl_xor(v, 8);
                if (m15 == 0) s_part[(quad*4 + rg)*64 + nt] = v;
            }
        }
        __syncthreads();

        // ======== exchange: atomicAdd partials into slot k%3 (validated R0)
        const int slot = k % 3;
        float* ab = accbuf + ((size_t)slot*NG + g)*1024;
        const int e0 = tid*2;
        {
            float v0 = s_part[e0]   + s_pmu[e0];
            float v1 = s_part[e0+1] + s_pmu[e0+1];
            __hip_atomic_fetch_add(&ab[e0],   v0, __ATOMIC_RELAXED,
                                   __HIP_MEMORY_SCOPE_AGENT);
            __hip_atomic_fetch_add(&ab[e0+1], v1, __ATOMIC_RELAXED,
                                   __HIP_MEMORY_SCOPE_AGENT);
        }
        // next-step u/dW into LDS NOW (so ks=2 precompute can run during spin).
        // Safe: GEMM1 reads of x and GEMM2 reads of s_dw all completed before
        // the previous barrier; adds above touch only global memory.
        if (k < Tt-2 && tid < 256) {
            _Float16 h = (_Float16)u_nx;
            s_xhi[r2][64+c2] = h; s_xlo[r2][64+c2] = (_Float16)(u_nx - (float)h);
            s_dw[r2][c2] = dw_nx;
        }
        __syncthreads();   // drains vmcnt: all adds complete; u/dW visible

        // release FIRST (don't delay peers), then fill the spin window with
        // next-step ks=2 (u-part) GEMM1 precompute, then tid0 spins.
        if (tid == 0)
            __hip_atomic_fetch_add(&cnt[g*CNT_STRIDE], 1u, __ATOMIC_RELEASE,
                                   __HIP_MEMORY_SCOPE_AGENT);
        if (k < Tt-2) {
            const _Float16* bp = w1base + (size_t)((tg*3 + 2)*2)*512 + lane*8;
            f16x8 bh = *(const f16x8*)bp;
            f16x8 bl = *(const f16x8*)(bp + 512);
            f16x8 ah = *(const f16x8*)&s_xhi[m15][64 + quad*8];
            f16x8 al = *(const f16x8*)&s_xlo[m15][64 + quad*8];
            f32x4 z = {0,0,0,0};
            pre0 = MFMA(ah, bh, z);
            pre1 = MFMA(ah, bl, z);
            pre2 = MFMA(al, bh, z);
        }
        if (tid == 0) {
            while (__hip_atomic_load(&cnt[g*CNT_STRIDE], __ATOMIC_RELAXED,
                                     __HIP_MEMORY_SCOPE_AGENT) < (unsigned)GB*(k+1))
                __builtin_amdgcn_s_sleep(2);
        }
        __syncthreads();

        // ======== read sum, y update, out write (wave j), zero (wave j+4)
        {
            const int r = e0 >> 6, n = e0 & 63;
            float sum0 = __hip_atomic_load(&ab[e0], __ATOMIC_RELAXED,
                                           __HIP_MEMORY_SCOPE_AGENT);
            float sum1 = __hip_atomic_load(&ab[e0+1], __ATOMIC_RELAXED,
                                           __HIP_MEMORY_SCOPE_AGENT);
            float ya = s_y[e0]   + sum0;
            float yb = s_y[e0+1] + sum1;
            s_y[e0] = ya; s_y[e0+1] = yb;
            _Float16 ha = (_Float16)ya, hb = (_Float16)yb;
            s_xhi[r][n] = ha;   s_xlo[r][n]   = (_Float16)(ya - (float)ha);
            s_xhi[r][n+1] = hb; s_xlo[r][n+1] = (_Float16)(yb - (float)hb);
            if ((tid >> 6) == j) {   // wave j writes this block's 128-elem chunk
                float2 o = {ya, yb};
                *(float2*)&out[((size_t)(k+1)*Bb + r0 + r)*64 + n] = o;
            }
            if (k >= 1 && (tid >> 6) == ((j+4)&7)) {
                // zero slot (k-1)%3; span (j+4)&7 -- bijective over the
                // group's 8 blocks, parallel with wave j's out-write
                float* zb = accbuf + ((size_t)((k-1)%3)*NG + g)*1024;
                __hip_atomic_store(&zb[e0],   0.f, __ATOMIC_RELAXED,
                                   __HIP_MEMORY_SCOPE_AGENT);
                __hip_atomic_store(&zb[e0+1], 0.f, __ATOMIC_RELAXED,
                                   __HIP_MEMORY_SCOPE_AGENT);
            }
        }
        __syncthreads();
    }
}

extern "C" void kernel_launch(void* const* d_in, const int* in_sizes, int n_in,
                              void* d_out, int out_size, void* d_ws, size_t ws_size,
                              hipStream_t stream) {
    const float* y0       = (const float*)d_in[0];
    const float* controls = (const float*)d_in[1];
    const float* noise    = (const float*)d_in[2];
    const float* W1_mu    = (const float*)d_in[3];
    const float* b1_mu    = (const float*)d_in[4];
    const float* W2_mu    = (const float*)d_in[5];
    const float* b2_mu    = (const float*)d_in[6];
    const float* W1_sg    = (const float*)d_in[7];
    const float* b1_sg    = (const float*)d_in[8];
    const float* W2_sg    = (const float*)d_in[9];
    const float* b2_sg    = (const float*)d_in[10];
    float* out = (float*)d_out;
    _Float16* wsh = (_Float16*)d_ws;
    float* accbuf = (float*)((char*)d_ws + ACC_BYTES_OFF);
    unsigned int* cnt = (unsigned int*)((char*)d_ws + CNT_BYTES_OFF);

    // zero accumulator slots + padded counters (ws is poisoned 0xAA each call)
    hipMemsetAsync((char*)d_ws + ACC_BYTES_OFF, 0,
                   (size_t)ACC_FLOATS*4 + (size_t)NG*CNT_STRIDE*4, stream);
    pack_weights<<<320, 256, 0, stream>>>(W1_mu, W2_mu, W1_sg, W2_sg, wsh);
    nsde_r7<<<NG*GB, NT, 0, stream>>>(y0, controls, noise,
                                      b1_mu, b2_mu, b1_sg, b2_sg,
                                      (const _Float16*)wsh,
                                      accbuf, cnt, out);
}

// Round 10
// 2104.662 us; speedup vs baseline: 2.4919x; 1.2045x over previous
//
#include <hip/hip_runtime.h>

// Neural SDE rollout, split-K across blocks. R9: XCD-local exchange, hardened.
// Theory: the 18us/step floor of the R0 structure is the ~900cy cross-XCD
// (MALL) round trip paid by every agent-scope exchange op. Remap blockIdx
// (g=bx&63, j=bx>>6) so all 8 blocks of a group land on one XCD under
// round-robin dispatch; run R0's EXACT exchange protocol (3-slot atomicAdd
// rotation + release counter) at WORKGROUP scope -> L2-local RMW, with
// sc0 (L1-bypass) polls/readback. Correctness never relies on the mapping
// (Guideline 16): a 3-phase runtime test -- (A) store->sc0-load visibility,
// (B) re-store/re-read staleness probe (catches write-through-to-MALL false
// positives), (C) workgroup-scope atomicAdd convergence (gates the actual
// mechanism) -- selects fast path vs byte-identical R0 agent-scope fallback,
// agreed group-wide via R0-proven agent-scope counters.

typedef _Float16 f16x8 __attribute__((ext_vector_type(8)));
typedef float    f32x4 __attribute__((ext_vector_type(4)));
typedef float    f32x2 __attribute__((ext_vector_type(2)));

#define MFMA(a,b,c) __builtin_amdgcn_mfma_f32_16x16x32_f16(a,b,c,0,0,0)

#define Bb 1024
#define Tt 128
#define NG 64          // groups
#define GB 8           // blocks per group (split-K over H=512 -> 64 cols each)
#define Rr 16          // rows per group (one MFMA M-tile)
#define NT 512         // threads per block (8 waves)
#define CNT_STRIDE 16
#define MAGIC1 0x1234ABCDu
#define MAGIC2 0xFEDC4321u

// packed fragment regions in d_ws (units: halves) -- identical pack to R0
#define W2SG_OFF 0
#define W2SG_HALVES (64*16*2*512)
#define W2MU_OFF (W2SG_OFF + W2SG_HALVES)
#define W2MU_HALVES (4*16*2*512)
#define W1MU_OFF (W2MU_OFF + W2MU_HALVES)
#define W1_HALVES (32*3*2*512)
#define W1SG_OFF (W1MU_OFF + W1_HALVES)
#define WS_HALVES (W1SG_OFF + W1_HALVES)
#define ACC_BYTES_OFF ((size_t)WS_HALVES * 2)
#define ACC_FLOATS (3 * NG * 1024)        // 3 slots x 64 groups x 16x64
#define CNT_OFF   (ACC_BYTES_OFF + (size_t)ACC_FLOATS*4)
// detection buffers (all zeroed): sizes in dwords
#define DTEST_DW  (NG*GB*16)
#define DW16      (NG*16)
#define DET_DW    (DTEST_DW + 6*DW16)     // dtest, dcntA, dcntB, dtc, dcntC, dok, dcnt2 -> note: 6 blocks of DW16 after dtest
#define WS_END    (CNT_OFF + (size_t)(DW16 + DET_DW)*4)

__global__ __launch_bounds__(256) void pack_weights(
    const float* __restrict__ W1_mu, const float* __restrict__ W2_mu,
    const float* __restrict__ W1_sg, const float* __restrict__ W2_sg,
    _Float16* __restrict__ wsh)
{
    int gid = blockIdx.x * 256 + threadIdx.x;
    if (gid >= 81920) return;
    const float* src; int ncols, kvalid; size_t dst;
    int id, tile, ks, lane;
    if (gid < 65536) {                 // W2_sg: 64 tiles x 16 ks x 64 lanes
        id = gid; tile = id >> 10; id &= 1023; ks = id >> 6; lane = id & 63;
        src = W2_sg; ncols = 1024; kvalid = 512;
        dst = W2SG_OFF + (size_t)((tile*16 + ks)*2) * 512 + lane*8;
    } else if (gid < 69632) {          // W2_mu: 4 x 16 x 64
        id = gid - 65536; tile = id >> 10; id &= 1023; ks = id >> 6; lane = id & 63;
        src = W2_mu; ncols = 64; kvalid = 512;
        dst = W2MU_OFF + (size_t)((tile*16 + ks)*2) * 512 + lane*8;
    } else if (gid < 75776) {          // W1_mu: 32 tiles x 3 ks x 64
        id = gid - 69632; tile = id / 192; id %= 192; ks = id >> 6; lane = id & 63;
        src = W1_mu; ncols = 512; kvalid = 80;
        dst = W1MU_OFF + (size_t)((tile*3 + ks)*2) * 512 + lane*8;
    } else {                           // W1_sg
        id = gid - 75776; tile = id / 192; id %= 192; ks = id >> 6; lane = id & 63;
        src = W1_sg; ncols = 512; kvalid = 80;
        dst = W1SG_OFF + (size_t)((tile*3 + ks)*2) * 512 + lane*8;
    }
    const int n  = tile*16 + (lane & 15);
    const int kb = ks*32 + ((lane >> 4) << 3);
    f16x8 hi8, lo8;
    #pragma unroll
    for (int jj = 0; jj < 8; ++jj) {
        int k = kb + jj;
        float wv = (k < kvalid) ? src[(size_t)k * ncols + n] : 0.f;
        _Float16 h = (_Float16)wv;
        hi8[jj] = h;
        lo8[jj] = (_Float16)(wv - (float)h);
    }
    *((f16x8*)(wsh + dst))       = hi8;
    *((f16x8*)(wsh + dst + 512)) = lo8;
}

__device__ __forceinline__ unsigned sc0_load_u32(const unsigned* p) {
    unsigned v;
    asm volatile("global_load_dword %0, %1, off sc0\n\ts_waitcnt vmcnt(0)"
                 : "=v"(v) : "v"((const void*)p) : "memory");
    return v;
}

__global__ __launch_bounds__(NT, 4) void nsde_r9(
    const float* __restrict__ y0, const float* __restrict__ controls,
    const float* __restrict__ noise,
    const float* __restrict__ b1_mu, const float* __restrict__ b2_mu,
    const float* __restrict__ b1_sg, const float* __restrict__ b2_sg,
    const _Float16* __restrict__ wf,
    float* __restrict__ accbuf, unsigned int* __restrict__ cnt,
    float* __restrict__ out)
{
    __shared__ _Float16 s_xhi[Rr][104], s_xlo[Rr][104];     // x, K=96 (+pad)
    __shared__ _Float16 s_hhi[2][Rr][72], s_hlo[2][Rr][72]; // h slices (64+pad)
    __shared__ float s_y[Rr*64];
    __shared__ float s_dw[Rr][16];
    __shared__ float s_part[Rr*64];
    __shared__ float s_pmu[Rr*64];
    __shared__ int   s_mode;

    const int tid  = threadIdx.x;
    const int lane = tid & 63, w = tid >> 6;
    const int m15  = lane & 15, quad = lane >> 4;
    const int g    = blockIdx.x & 63;       // group; XCD = (j*64+g)%8 = g%8
    const int j    = blockIdx.x >> 6;       // K-slice id
    const int r0   = g * Rr;

    // detection buffers, derived from cnt (cnt itself = NG*16 dwords)
    unsigned* dtest = cnt + NG*16;          // NG*GB*16
    unsigned* dcntA = dtest + NG*GB*16;     // NG*16 each below
    unsigned* dcntB = dcntA + NG*16;
    unsigned* dtc   = dcntB + NG*16;
    unsigned* dcntC = dtc   + NG*16;
    unsigned* dok   = dcntC + NG*16;
    unsigned* dcnt2 = dok   + NG*16;

    // per-wave constants (R0 verbatim)
    const int l  = w >> 2;
    const int ct = w & 3;
    const int tg = j*4 + ct;
    const _Float16* w1base = wf + (l ? W1SG_OFF : W1MU_OFF);
    const float bias1 = (l ? b1_sg : b1_mu)[j*64 + ct*16 + m15];
    float b2v[8];
    #pragma unroll
    for (int t = 0; t < 8; ++t)
        b2v[t] = (j == 0) ? b2_sg[(w + t*8)*16 + m15] : 0.f;
    const float b2m = (w < 4 && j == 0) ? b2_mu[w*16 + m15] * 0.01f : 0.f;

    // ======== coherence-domain detection (3-phase, once) ========
    if (tid == 0) {
        volatile unsigned* my = (volatile unsigned*)&dtest[(size_t)(g*GB + j)*16];
        int ok = 1;
        // phase A: plain store -> sc0 load visibility
        *my = MAGIC1;
        asm volatile("s_waitcnt vmcnt(0)" ::: "memory");
        __hip_atomic_fetch_add(&dcntA[g*16], 1u, __ATOMIC_RELEASE,
                               __HIP_MEMORY_SCOPE_AGENT);
        while (__hip_atomic_load(&dcntA[g*16], __ATOMIC_RELAXED,
                                 __HIP_MEMORY_SCOPE_AGENT) < (unsigned)GB)
            __builtin_amdgcn_s_sleep(2);
        for (int b = 0; b < GB; ++b)
            ok &= (sc0_load_u32(&dtest[(size_t)(g*GB + b)*16]) == MAGIC1);
        // phase B: RE-store same address, re-read -- stale-line probe
        *my = MAGIC2;
        asm volatile("s_waitcnt vmcnt(0)" ::: "memory");
        __hip_atomic_fetch_add(&dcntB[g*16], 1u, __ATOMIC_RELEASE,
                               __HIP_MEMORY_SCOPE_AGENT);
        while (__hip_atomic_load(&dcntB[g*16], __ATOMIC_RELAXED,
                                 __HIP_MEMORY_SCOPE_AGENT) < (unsigned)GB)
            __builtin_amdgcn_s_sleep(2);
        for (int b = 0; b < GB; ++b)
            ok &= (sc0_load_u32(&dtest[(size_t)(g*GB + b)*16]) == MAGIC2);
        // phase C: workgroup-scope atomicAdd convergence (the real mechanism)
        __hip_atomic_fetch_add(&dtc[g*16], 1u, __ATOMIC_RELAXED,
                               __HIP_MEMORY_SCOPE_WORKGROUP);
        asm volatile("s_waitcnt vmcnt(0)" ::: "memory");
        __hip_atomic_fetch_add(&dcntC[g*16], 1u, __ATOMIC_RELEASE,
                               __HIP_MEMORY_SCOPE_AGENT);
        while (__hip_atomic_load(&dcntC[g*16], __ATOMIC_RELAXED,
                                 __HIP_MEMORY_SCOPE_AGENT) < (unsigned)GB)
            __builtin_amdgcn_s_sleep(2);
        ok &= (sc0_load_u32(&dtc[g*16]) == (unsigned)GB);
        // group-wide agreement (agent scope, R0-proven)
        __hip_atomic_fetch_add(&dok[g*16], ok ? 1u : 0u, __ATOMIC_RELEASE,
                               __HIP_MEMORY_SCOPE_AGENT);
        __hip_atomic_fetch_add(&dcnt2[g*16], 1u, __ATOMIC_RELEASE,
                               __HIP_MEMORY_SCOPE_AGENT);
        while (__hip_atomic_load(&dcnt2[g*16], __ATOMIC_RELAXED,
                                 __HIP_MEMORY_SCOPE_AGENT) < (unsigned)GB)
            __builtin_amdgcn_s_sleep(2);
        s_mode = (__hip_atomic_load(&dok[g*16], __ATOMIC_RELAXED,
                                    __HIP_MEMORY_SCOPE_AGENT) == (unsigned)GB);
    }
    __syncthreads();
    const bool local = (s_mode != 0);

    // ---- init (R0 verbatim)
    for (int e = tid; e < Rr*24; e += NT) {
        int r = e / 24, c = 80 + e % 24;
        s_xhi[r][c] = (_Float16)0.f; s_xlo[r][c] = (_Float16)0.f;
    }
    if (tid < 256) {
        int e0 = tid*4, r = e0 >> 6, n = e0 & 63;
        float4 yv = *(const float4*)&y0[(size_t)(r0 + r)*64 + n];
        float vv[4] = {yv.x, yv.y, yv.z, yv.w};
        #pragma unroll
        for (int q = 0; q < 4; ++q) {
            s_y[e0+q] = vv[q];
            _Float16 h = (_Float16)vv[q];
            s_xhi[r][n+q] = h; s_xlo[r][n+q] = (_Float16)(vv[q] - (float)h);
        }
        if ((tid >> 5) == j)
            *(float4*)&out[(size_t)(r0 + r)*64 + n] = yv;
        int rr2 = tid >> 4, cc2 = tid & 15;
        float u = controls[cc2];
        _Float16 h = (_Float16)u;
        s_xhi[rr2][64+cc2] = h; s_xlo[rr2][64+cc2] = (_Float16)(u - (float)h);
        s_dw[rr2][cc2] = noise[(size_t)(r0 + rr2)*16 + cc2] * 0.1f;
    }
    __syncthreads();

    for (int k = 0; k < Tt-1; ++k) {
        // ======== GEMM1 (R0 verbatim)
        {
            f32x4 a0 = {0,0,0,0}, a1 = {0,0,0,0}, a2 = {0,0,0,0};
            #pragma unroll
            for (int ks = 0; ks < 3; ++ks) {
                const _Float16* bp = w1base + (size_t)((tg*3 + ks)*2)*512 + lane*8;
                f16x8 bh = *(const f16x8*)bp;
                f16x8 bl = *(const f16x8*)(bp + 512);
                f16x8 ah = *(const f16x8*)&s_xhi[m15][ks*32 + quad*8];
                f16x8 al = *(const f16x8*)&s_xlo[m15][ks*32 + quad*8];
                a0 = MFMA(ah, bh, a0);
                a1 = MFMA(ah, bl, a1);
                a2 = MFMA(al, bh, a2);
            }
            f32x4 s = a0 + a1 + a2;
            #pragma unroll
            for (int rg = 0; rg < 4; ++rg) {
                int row = quad*4 + rg;
                float v = fmaxf(s[rg] + bias1, 0.f);
                _Float16 h = (_Float16)v;
                s_hhi[l][row][ct*16 + m15] = h;
                s_hlo[l][row][ct*16 + m15] = (_Float16)(v - (float)h);
            }
        }
        float u_nx = 0.f, dw_nx = 0.f;
        const int r2 = tid >> 4, c2 = tid & 15;
        if (k < Tt-2 && tid < 256) {
            u_nx  = controls[(size_t)(k+1)*16 + c2];
            dw_nx = noise[((size_t)(k+1)*Bb + r0 + r2)*16 + c2] * 0.1f;
        }
        __syncthreads();

        // ======== GEMM2 (R0 verbatim)
        float dwv[4];
        #pragma unroll
        for (int rg = 0; rg < 4; ++rg)
            dwv[rg] = s_dw[quad*4 + rg][m15];

        if (w < 4) {
            f16x8 Mh0 = *(const f16x8*)&s_hhi[0][m15][quad*8];
            f16x8 Ml0 = *(const f16x8*)&s_hlo[0][m15][quad*8];
            f16x8 Mh1 = *(const f16x8*)&s_hhi[0][m15][32 + quad*8];
            f16x8 Ml1 = *(const f16x8*)&s_hlo[0][m15][32 + quad*8];
            const _Float16* bp = wf + W2MU_OFF + (size_t)((w*16 + 2*j)*2)*512 + lane*8;
            f16x8 bh0 = *(const f16x8*)(bp);
            f16x8 bl0 = *(const f16x8*)(bp + 512);
            f16x8 bh1 = *(const f16x8*)(bp + 1024);
            f16x8 bl1 = *(const f16x8*)(bp + 1536);
            f32x4 hh = {0,0,0,0}, hl = {0,0,0,0}, lh = {0,0,0,0};
            hh = MFMA(Mh0, bh0, hh); hl = MFMA(Mh0, bl0, hl); lh = MFMA(Ml0, bh0, lh);
            hh = MFMA(Mh1, bh1, hh); hl = MFMA(Mh1, bl1, hl); lh = MFMA(Ml1, bh1, lh);
            f32x4 s = hh + hl + lh;
            #pragma unroll
            for (int rg = 0; rg < 4; ++rg)
                s_pmu[(quad*4 + rg)*64 + w*16 + m15] = s[rg]*0.01f + b2m;
        }

        f16x8 Ah0 = *(const f16x8*)&s_hhi[1][m15][quad*8];
        f16x8 Al0 = *(const f16x8*)&s_hlo[1][m15][quad*8];
        f16x8 Ah1 = *(const f16x8*)&s_hhi[1][m15][32 + quad*8];
        f16x8 Al1 = *(const f16x8*)&s_hlo[1][m15][32 + quad*8];
        #pragma unroll 2
        for (int t = 0; t < 8; ++t) {
            const int nt = w + t*8;
            const _Float16* bp = wf + W2SG_OFF + (size_t)((nt*16 + 2*j)*2)*512 + lane*8;
            f16x8 bh0 = *(const f16x8*)(bp);
            f16x8 bl0 = *(const f16x8*)(bp + 512);
            f16x8 bh1 = *(const f16x8*)(bp + 1024);
            f16x8 bl1 = *(const f16x8*)(bp + 1536);
            f32x4 hh = {0,0,0,0}, hl = {0,0,0,0}, lh = {0,0,0,0};
            hh = MFMA(Ah0, bh0, hh); hl = MFMA(Ah0, bl0, hl); lh = MFMA(Al0, bh0, lh);
            hh = MFMA(Ah1, bh1, hh); hl = MFMA(Ah1, bl1, hl); lh = MFMA(Al1, bh1, lh);
            f32x4 s = hh + hl + lh;
            #pragma unroll
            for (int rg = 0; rg < 4; ++rg) {
                float v = (s[rg] + b2v[t]) * dwv[rg];
                v += __shfl_xor(v, 1); v += __shfl_xor(v, 2);
                v += __shfl_xor(v, 4); v += __shfl_xor(v, 8);
                if (m15 == 0) s_part[(quad*4 + rg)*64 + nt] = v;
            }
        }
        __syncthreads();

        // ======== exchange: R0 protocol, scope selected by detection
        const int slot = k % 3;
        float* ab = accbuf + ((size_t)slot*NG + g)*1024;
        const int e0 = tid*2;
        {
            float v0 = s_part[e0]   + s_pmu[e0];
            float v1 = s_part[e0+1] + s_pmu[e0+1];
            if (local) {
                __hip_atomic_fetch_add(&ab[e0],   v0, __ATOMIC_RELAXED,
                                       __HIP_MEMORY_SCOPE_WORKGROUP);
                __hip_atomic_fetch_add(&ab[e0+1], v1, __ATOMIC_RELAXED,
                                       __HIP_MEMORY_SCOPE_WORKGROUP);
            } else {
                __hip_atomic_fetch_add(&ab[e0],   v0, __ATOMIC_RELAXED,
                                       __HIP_MEMORY_SCOPE_AGENT);
                __hip_atomic_fetch_add(&ab[e0+1], v1, __ATOMIC_RELAXED,
                                       __HIP_MEMORY_SCOPE_AGENT);
            }
        }
        __syncthreads();   // drains vmcnt: all adds complete at their L2 tier
        if (tid == 0) {
            if (local) {
                __hip_atomic_fetch_add(&cnt[g*CNT_STRIDE], 1u, __ATOMIC_RELEASE,
                                       __HIP_MEMORY_SCOPE_WORKGROUP);
                const unsigned tgt = (unsigned)GB*(k+1);
                for (;;) {
                    unsigned v = sc0_load_u32(&cnt[g*CNT_STRIDE]);
                    if (v >= tgt) break;
                    __builtin_amdgcn_s_sleep(2);
                }
            } else {
                __hip_atomic_fetch_add(&cnt[g*CNT_STRIDE], 1u, __ATOMIC_RELEASE,
                                       __HIP_MEMORY_SCOPE_AGENT);
                while (__hip_atomic_load(&cnt[g*CNT_STRIDE], __ATOMIC_RELAXED,
                                         __HIP_MEMORY_SCOPE_AGENT) < (unsigned)GB*(k+1))
                    __builtin_amdgcn_s_sleep(2);
            }
        }
        __syncthreads();

        // ======== read sum, y update, out write, next x/dW build
        {
            const int r = e0 >> 6, n = e0 & 63;
            float sum0, sum1;
            if (local) {
                f32x2 sv;
                asm volatile("global_load_dwordx2 %0, %1, off sc0\n\t"
                             "s_waitcnt vmcnt(0)"
                             : "=v"(sv) : "v"((const void*)&ab[e0]) : "memory");
                sum0 = sv[0]; sum1 = sv[1];
            } else {
                sum0 = __hip_atomic_load(&ab[e0], __ATOMIC_RELAXED,
                                         __HIP_MEMORY_SCOPE_AGENT);
                sum1 = __hip_atomic_load(&ab[e0+1], __ATOMIC_RELAXED,
                                         __HIP_MEMORY_SCOPE_AGENT);
            }
            float ya = s_y[e0]   + sum0;
            float yb = s_y[e0+1] + sum1;
            s_y[e0] = ya; s_y[e0+1] = yb;
            _Float16 ha = (_Float16)ya, hb = (_Float16)yb;
            s_xhi[r][n] = ha;   s_xlo[r][n]   = (_Float16)(ya - (float)ha);
            s_xhi[r][n+1] = hb; s_xlo[r][n+1] = (_Float16)(yb - (float)hb);
            if ((tid >> 6) == j) {   // wave j writes this block's 128-elem chunk
                float2 o = {ya, yb};
                *(float2*)&out[((size_t)(k+1)*Bb + r0 + r)*64 + n] = o;
                if (k >= 1) {        // zero slot (k-1)%3 (3-slot rotation safe)
                    float* zb = accbuf + ((size_t)((k-1)%3)*NG + g)*1024;
                    if (local) {
                        *(volatile float*)&zb[e0]   = 0.f;
                        *(volatile float*)&zb[e0+1] = 0.f;
                    } else {
                        __hip_atomic_store(&zb[e0],   0.f, __ATOMIC_RELAXED,
                                           __HIP_MEMORY_SCOPE_AGENT);
                        __hip_atomic_store(&zb[e0+1], 0.f, __ATOMIC_RELAXED,
                                           __HIP_MEMORY_SCOPE_AGENT);
                    }
                }
            }
        }
        if (k < Tt-2 && tid < 256) {
            _Float16 h = (_Float16)u_nx;
            s_xhi[r2][64+c2] = h; s_xlo[r2][64+c2] = (_Float16)(u_nx - (float)h);
            s_dw[r2][c2] = dw_nx;
        }
        __syncthreads();
    }
}

extern "C" void kernel_launch(void* const* d_in, const int* in_sizes, int n_in,
                              void* d_out, int out_size, void* d_ws, size_t ws_size,
                              hipStream_t stream) {
    const float* y0       = (const float*)d_in[0];
    const float* controls = (const float*)d_in[1];
    const float* noise    = (const float*)d_in[2];
    const float* W1_mu    = (const float*)d_in[3];
    const float* b1_mu    = (const float*)d_in[4];
    const float* W2_mu    = (const float*)d_in[5];
    const float* b2_mu    = (const float*)d_in[6];
    const float* W1_sg    = (const float*)d_in[7];
    const float* b1_sg    = (const float*)d_in[8];
    const float* W2_sg    = (const float*)d_in[9];
    const float* b2_sg    = (const float*)d_in[10];
    float* out = (float*)d_out;
    _Float16* wsh = (_Float16*)d_ws;
    float* accbuf = (float*)((char*)d_ws + ACC_BYTES_OFF);
    unsigned int* cnt = (unsigned int*)((char*)d_ws + CNT_OFF);

    // zero accumulator slots + counters + all detection buffers
    // (ws is poisoned 0xAA each call; detection relies on zeros)
    hipMemsetAsync((char*)d_ws + ACC_BYTES_OFF, 0,
                   WS_END - ACC_BYTES_OFF, stream);
    pack_weights<<<320, 256, 0, stream>>>(W1_mu, W2_mu, W1_sg, W2_sg, wsh);
    nsde_r9<<<NG*GB, NT, 0, stream>>>(y0, controls, noise,
                                      b1_mu, b2_mu, b1_sg, b2_sg,
                                      (const _Float16*)wsh,
                                      accbuf, cnt, out);
}